// Round 8
// baseline (972.098 us; speedup 1.0000x reference)
//
#include <hip/hip_runtime.h>
#include <math.h>

#define TPB 256
#define NWAVE (TPB / 64)
#define POOLCAP 512
#define FASTCAP 256
#define KTOP 10

typedef float floatx4 __attribute__((ext_vector_type(4)));

__device__ inline float wredMax(float v) {
#pragma unroll
  for (int o = 32; o >= 1; o >>= 1) v = fmaxf(v, __shfl_xor(v, o));
  return v;
}
__device__ inline float wredMin(float v) {
#pragma unroll
  for (int o = 32; o >= 1; o >>= 1) v = fminf(v, __shfl_xor(v, o));
  return v;
}
__device__ inline float wredSum(float v) {
#pragma unroll
  for (int o = 32; o >= 1; o >>= 1) v += __shfl_xor(v, o);
  return v;
}
// argmax across wave: max value, ties -> lowest index (jax.lax.top_k stable)
__device__ inline void wargmax(float& v, int& i) {
#pragma unroll
  for (int o = 32; o >= 1; o >>= 1) {
    float ov = __shfl_xor(v, o);
    int   oi = __shfl_xor(i, o);
    if (ov > v || (ov == v && oi < i)) { v = ov; i = oi; }
  }
}

struct SMem {
  float pv[POOLCAP];
  int   pi[POOLCAP];
  float redmin[NWAVE];
  float redmax[NWAVE];
  float redsum[NWAVE];
  float wwv[NWAVE];
  int   wwi[NWAVE];
  float kept_v[KTOP];
  int   kept_i[KTOP];
  float pk[KTOP];      // exp(kept_v)*invZ
  int   pool_cnt;
  float g_m, g_v, g_sall, g_zy;
  float c_prest, c_ptrue;
};

__global__ __launch_bounds__(TPB) void fedquit_kernel(
    const float* __restrict__ zg, const int* __restrict__ yv,
    float* __restrict__ out, int B, int C) {
  __shared__ SMem S;

  const int tid  = threadIdx.x;
  const int wid  = tid >> 6;
  const int lane = tid & 63;
  const int b    = blockIdx.x;

  const float* zr = zg + (size_t)b * C;
  float* orow = out + (size_t)b * C;
  const int y = yv[b];
  const int C4 = C >> 2;
  const floatx4* zr4 = (const floatx4*)zr;
  const int Keff = KTOP < (C - 1) ? KTOP : (C - 1);

  if (tid == 0) S.g_zy = zr[y];   // true logit, needed once

  // ---- Pass A (single HBM stream, 4x unrolled for MLP): min/max/sum-exp over
  // ALL elements (no per-element y test; y's contribution removed afterwards).
  // Raw exp safe in fp32: |z| ~ O(20) << 88.
  float lmin = INFINITY, lmax = -INFINITY, lsum = 0.0f;
  {
    int i = tid;
    for (; i + 3 * TPB < C4; i += 4 * TPB) {
      floatx4 x0 = zr4[i];
      floatx4 x1 = zr4[i + TPB];
      floatx4 x2 = zr4[i + 2 * TPB];
      floatx4 x3 = zr4[i + 3 * TPB];
      lmin = fminf(lmin, fminf(fminf(x0.x, x0.y), fminf(x0.z, x0.w)));
      lmax = fmaxf(lmax, fmaxf(fmaxf(x0.x, x0.y), fmaxf(x0.z, x0.w)));
      lsum += __expf(x0.x) + __expf(x0.y) + __expf(x0.z) + __expf(x0.w);
      lmin = fminf(lmin, fminf(fminf(x1.x, x1.y), fminf(x1.z, x1.w)));
      lmax = fmaxf(lmax, fmaxf(fmaxf(x1.x, x1.y), fmaxf(x1.z, x1.w)));
      lsum += __expf(x1.x) + __expf(x1.y) + __expf(x1.z) + __expf(x1.w);
      lmin = fminf(lmin, fminf(fminf(x2.x, x2.y), fminf(x2.z, x2.w)));
      lmax = fmaxf(lmax, fmaxf(fmaxf(x2.x, x2.y), fmaxf(x2.z, x2.w)));
      lsum += __expf(x2.x) + __expf(x2.y) + __expf(x2.z) + __expf(x2.w);
      lmin = fminf(lmin, fminf(fminf(x3.x, x3.y), fminf(x3.z, x3.w)));
      lmax = fmaxf(lmax, fmaxf(fmaxf(x3.x, x3.y), fmaxf(x3.z, x3.w)));
      lsum += __expf(x3.x) + __expf(x3.y) + __expf(x3.z) + __expf(x3.w);
    }
    for (; i < C4; i += TPB) {
      floatx4 x = zr4[i];
      lmin = fminf(lmin, fminf(fminf(x.x, x.y), fminf(x.z, x.w)));
      lmax = fmaxf(lmax, fmaxf(fmaxf(x.x, x.y), fmaxf(x.z, x.w)));
      lsum += __expf(x.x) + __expf(x.y) + __expf(x.z) + __expf(x.w);
    }
    for (int j = (C4 << 2) + tid; j < C; j += TPB) {
      float z = zr[j];
      lmin = fminf(lmin, z);
      lmax = fmaxf(lmax, z);
      lsum += __expf(z);
    }
  }
  const float tmax = lmax;   // per-thread max of OWN elements (pool filter), free

  lmin = wredMin(lmin); lmax = wredMax(lmax); lsum = wredSum(lsum);
  if (lane == 0) { S.redmin[wid] = lmin; S.redmax[wid] = lmax; S.redsum[wid] = lsum; }
  __syncthreads();
  if (tid == 0) {
    float v = INFINITY, mm = -INFINITY, s = 0.0f;
#pragma unroll
    for (int w = 0; w < NWAVE; ++w) {
      v = fminf(v, S.redmin[w]);
      mm = fmaxf(mm, S.redmax[w]);
      s += S.redsum[w];
    }
    S.g_m = mm; S.g_v = v;
    S.g_sall = s - __expf(S.g_zy);   // exclude true logit from non-true sum
  }
  __syncthreads();
  const float m    = S.g_m;     // overall max (pool threshold base)
  const float vmin = S.g_v;
  const float Sall = S.g_sall;

  // ---- Pool pass: only threads whose OWN max passes re-scan their elements ----
  float delta = 5.0f;
  int pc = 0;
  for (int tries = 0; tries < 24; ++tries) {
    if (tid == 0) S.pool_cnt = 0;
    __syncthreads();
    const float lim = m - delta;
    if (tmax > lim) {
      for (int i = tid; i < C4; i += TPB) {
        floatx4 x = zr4[i];
        int j = i << 2;
        if (x.x > lim && j + 0 != y) { int p = atomicAdd(&S.pool_cnt, 1); if (p < POOLCAP) { S.pv[p] = x.x; S.pi[p] = j + 0; } }
        if (x.y > lim && j + 1 != y) { int p = atomicAdd(&S.pool_cnt, 1); if (p < POOLCAP) { S.pv[p] = x.y; S.pi[p] = j + 1; } }
        if (x.z > lim && j + 2 != y) { int p = atomicAdd(&S.pool_cnt, 1); if (p < POOLCAP) { S.pv[p] = x.z; S.pi[p] = j + 2; } }
        if (x.w > lim && j + 3 != y) { int p = atomicAdd(&S.pool_cnt, 1); if (p < POOLCAP) { S.pv[p] = x.w; S.pi[p] = j + 3; } }
      }
      for (int j = (C4 << 2) + tid; j < C; j += TPB) {
        float z = zr[j];
        if (z > lim && j != y) { int p = atomicAdd(&S.pool_cnt, 1); if (p < POOLCAP) { S.pv[p] = z; S.pi[p] = j; } }
      }
    }
    __syncthreads();
    pc = S.pool_cnt;
    if (pc >= Keff && pc <= FASTCAP) break;
    if (pc < Keff) delta *= 2.0f; else delta *= 0.5f;
    __syncthreads();   // all read pc before next reset
  }

  const bool fast = (pc >= Keff && pc <= FASTCAP);
  const bool mid  = (!fast && pc > FASTCAP && pc <= POOLCAP);

  // ---- Top-Keff extraction (value desc, index asc == jax stable) ----
  if (fast) {
    // Barrier-free: wave 0 holds up to 256 pool entries in registers.
    if (wid == 0) {
      float v0 = (lane < pc)       ? S.pv[lane]       : -INFINITY;
      float v1 = (lane + 64 < pc)  ? S.pv[lane + 64]  : -INFINITY;
      float v2 = (lane + 128 < pc) ? S.pv[lane + 128] : -INFINITY;
      float v3 = (lane + 192 < pc) ? S.pv[lane + 192] : -INFINITY;
      int   i0 = (lane < pc)       ? S.pi[lane]       : 0x7fffffff;
      int   i1 = (lane + 64 < pc)  ? S.pi[lane + 64]  : 0x7fffffff;
      int   i2 = (lane + 128 < pc) ? S.pi[lane + 128] : 0x7fffffff;
      int   i3 = (lane + 192 < pc) ? S.pi[lane + 192] : 0x7fffffff;
      for (int r = 0; r < Keff; ++r) {
        float bv = v0; int bi = i0;
        if (v1 > bv || (v1 == bv && i1 < bi)) { bv = v1; bi = i1; }
        if (v2 > bv || (v2 == bv && i2 < bi)) { bv = v2; bi = i2; }
        if (v3 > bv || (v3 == bv && i3 < bi)) { bv = v3; bi = i3; }
        wargmax(bv, bi);
        if (lane == 0) { S.kept_v[r] = bv; S.kept_i[r] = bi; }
        // invalidate the winner (index is unique)
        if (i0 == bi) v0 = -INFINITY;
        if (i1 == bi) v1 = -INFINITY;
        if (i2 == bi) v2 = -INFINITY;
        if (i3 == bi) v3 = -INFINITY;
      }
    }
  } else if (mid) {
    // LDS multi-round over pool (rare).
    int pooled_n = pc < POOLCAP ? pc : POOLCAP;
    for (int r = 0; r < Keff; ++r) {
      float bv = -INFINITY; int bi = 0x7fffffff;
      for (int t = tid; t < pooled_n; t += TPB) {
        float vv = S.pv[t]; int ii = S.pi[t];
        if (vv > bv || (vv == bv && ii < bi)) { bv = vv; bi = ii; }
      }
      wargmax(bv, bi);
      if (lane == 0) { S.wwv[wid] = bv; S.wwi[wid] = bi; }
      __syncthreads();
      if (tid == 0) {
        float wv = -INFINITY; int wi = 0x7fffffff;
#pragma unroll
        for (int w = 0; w < NWAVE; ++w) {
          if (S.wwv[w] > wv || (S.wwv[w] == wv && S.wwi[w] < wi)) { wv = S.wwv[w]; wi = S.wwi[w]; }
        }
        S.kept_v[r] = wv; S.kept_i[r] = wi;
      }
      __syncthreads();
      int wi = S.kept_i[r];
      for (int t = tid; t < pooled_n; t += TPB)
        if (S.pi[t] == wi) S.pv[t] = -INFINITY;
      __syncthreads();
    }
  } else {
    // Guaranteed-correct fallback: Keff rounds of full-row argmax (pathological).
    for (int r = 0; r < Keff; ++r) {
      float bv = -INFINITY; int bi = 0x7fffffff;
      for (int i = tid; i < C; i += TPB) {
        if (i == y) continue;
        float z = zr[i];
        bool skip = false;
        for (int k = 0; k < r; ++k) if (S.kept_i[k] == i) skip = true;
        if (!skip && (z > bv || (z == bv && i < bi))) { bv = z; bi = i; }
      }
      wargmax(bv, bi);
      if (lane == 0) { S.wwv[wid] = bv; S.wwi[wid] = bi; }
      __syncthreads();
      if (tid == 0) {
        float wv = -INFINITY; int wi = 0x7fffffff;
#pragma unroll
        for (int w = 0; w < NWAVE; ++w) {
          if (S.wwv[w] > wv || (S.wwv[w] == wv && S.wwi[w] < wi)) { wv = S.wwv[w]; wi = S.wwi[w]; }
        }
        S.kept_v[r] = wv; S.kept_i[r] = wi;
      }
      __syncthreads();
    }
  }
  __syncthreads();

  // ---- Per-row constants (Z = Sall + e^v exactly; rest-replace preserves sum) ----
  if (tid == 0) {
    float Stop = 0.0f;
    for (int r = 0; r < Keff; ++r) Stop += __expf(S.kept_v[r]);
    float ev = __expf(vmin);
    float invZ = 1.0f / (Sall + ev);
    float Srest = Sall - Stop;
    if (Srest < 0.0f) Srest = 0.0f;
    float MR = (float)(C - 1 - Keff);
    if (MR < 1.0f) MR = 1.0f;
    S.c_prest = (Srest / MR) * invZ;
    S.c_ptrue = ev * invZ;
    for (int r = 0; r < KTOP; ++r) {
      if (r < Keff) {
        S.pk[r] = __expf(S.kept_v[r]) * invZ;
      } else {
        S.pk[r] = 0.0f;
        S.kept_i[r] = -1;
      }
    }
  }
  __syncthreads();

  const float p_rest = S.c_prest;
  const float p_true = S.c_ptrue;
  int   ki[KTOP];
  float pkv[KTOP];
  int   sv[KTOP];
#pragma unroll
  for (int k = 0; k < KTOP; ++k) {
    ki[k]  = S.kept_i[k];
    pkv[k] = S.pk[k];
    sv[k]  = ki[k] < 0 ? -1 : (ki[k] >> 2);
  }
  const int svy = y >> 2;

  // ---- Fill pass: NO input read. p_rest everywhere; patch 10 kept + true inline ----
  floatx4* orow4 = (floatx4*)orow;
  const floatx4 fillv = {p_rest, p_rest, p_rest, p_rest};
  for (int i = tid; i < C4; i += TPB) {
    floatx4 o = fillv;
    bool sp = (i == svy);
#pragma unroll
    for (int k = 0; k < KTOP; ++k) sp |= (i == sv[k]);
    if (sp) {
      int j = i << 2;
#pragma unroll
      for (int l = 0; l < 4; ++l) {
        float p = p_rest;
#pragma unroll
        for (int k = 0; k < KTOP; ++k)
          if (j + l == ki[k]) p = pkv[k];
        if (j + l == y) p = p_true;
        o[l] = p;
      }
    }
    __builtin_nontemporal_store(o, &orow4[i]);
  }
  for (int j = (C4 << 2) + tid; j < C; j += TPB) {
    float p = p_rest;
#pragma unroll
    for (int k = 0; k < KTOP; ++k)
      if (j == ki[k]) p = pkv[k];
    if (j == y) p = p_true;
    __builtin_nontemporal_store(p, &orow[j]);
  }
}

extern "C" void kernel_launch(void* const* d_in, const int* in_sizes, int n_in,
                              void* d_out, int out_size, void* d_ws, size_t ws_size,
                              hipStream_t stream) {
  const float* zg = (const float*)d_in[0];
  const int* y    = (const int*)d_in[1];
  float* out      = (float*)d_out;
  const int B = in_sizes[1];
  const int C = in_sizes[0] / B;

  fedquit_kernel<<<B, TPB, 0, stream>>>(zg, y, out, B, C);
}

// Round 9
// 631.479 us; speedup vs baseline: 1.5394x; 1.5394x over previous
//
#include <hip/hip_runtime.h>
#include <math.h>
#include <limits.h>

#define SEGS 8
#define KTOP 10
#define TPB1 256
#define TPB3 256

typedef float floatx4 __attribute__((ext_vector_type(4)));

__device__ inline float wredMin(float v) {
#pragma unroll
  for (int o = 32; o >= 1; o >>= 1) v = fminf(v, __shfl_xor(v, o));
  return v;
}
__device__ inline float wredSum(float v) {
#pragma unroll
  for (int o = 32; o >= 1; o >>= 1) v += __shfl_xor(v, o);
  return v;
}
// argmax across wave: max value, ties -> lowest index (jax.lax.top_k stable)
__device__ inline void wargmax(float& v, int& i) {
#pragma unroll
  for (int o = 32; o >= 1; o >>= 1) {
    float ov = __shfl_xor(v, o);
    int   oi = __shfl_xor(i, o);
    if (ov > v || (ov == v && oi < i)) { v = ov; i = oi; }
  }
}

// ---------------- K1: per-segment stats + exact segment top-10 ----------------
__global__ __launch_bounds__(TPB1) void k1_seg(
    const float* __restrict__ zg, const int* __restrict__ yv,
    float* __restrict__ smin, float* __restrict__ ssum,
    float* __restrict__ cv, int* __restrict__ ci, int B, int C) {
  __shared__ float wcv[4 * KTOP];
  __shared__ int   wci[4 * KTOP];
  __shared__ float rmn[4], rsm[4];

  const int rs  = blockIdx.x;
  const int row = rs / SEGS, seg = rs - row * SEGS;
  const int C4  = C >> 2;
  const int L4  = (C4 + SEGS - 1) / SEGS;
  const int g_lo = seg * L4;
  const int g_hi = min(g_lo + L4, C4);
  const int ng   = g_hi - g_lo;   // float4-groups in this segment

  const int y = yv[row];
  const floatx4* zr4 = (const floatx4*)(zg + (size_t)row * C);

  const int tid = threadIdx.x;
  const int wid = tid >> 6, lane = tid & 63;

  float lmin = INFINITY, lsum = 0.0f;
  floatx4 c0, c1, c2, c3;                 // candidate values (y suppressed)
  const int q0 = tid, q1 = tid + TPB1, q2 = tid + 2 * TPB1, q3 = tid + 3 * TPB1;

#define K1LOAD(CQ, Q)                                                       \
  if ((Q) < ng) {                                                           \
    floatx4 x = zr4[g_lo + (Q)];                                            \
    lmin = fminf(lmin, fminf(fminf(x.x, x.y), fminf(x.z, x.w)));            \
    lsum += __expf(x.x) + __expf(x.y) + __expf(x.z) + __expf(x.w);          \
    int j0 = (g_lo + (Q)) << 2;                                             \
    CQ = x;                                                                 \
    if (j0 + 0 == y) CQ.x = -INFINITY;                                      \
    if (j0 + 1 == y) CQ.y = -INFINITY;                                      \
    if (j0 + 2 == y) CQ.z = -INFINITY;                                      \
    if (j0 + 3 == y) CQ.w = -INFINITY;                                      \
  } else {                                                                  \
    CQ.x = -INFINITY; CQ.y = -INFINITY; CQ.z = -INFINITY; CQ.w = -INFINITY; \
  }
  K1LOAD(c0, q0)
  K1LOAD(c1, q1)
  K1LOAD(c2, q2)
  K1LOAD(c3, q3)
#undef K1LOAD

  // local argmax over my 16 candidate slots (value desc, index asc)
  float bv; int bi;
#define SC(CQ, Q)                                                            \
  { _Pragma("unroll") for (int l = 0; l < 4; ++l) {                          \
      float vv = CQ[l];                                                      \
      int ii = ((Q) < ng) ? (((g_lo + (Q)) << 2) + l) : INT_MAX;             \
      if (vv > bv || (vv == bv && ii < bi)) { bv = vv; bi = ii; } } }
#define RESCAN() { bv = -INFINITY; bi = INT_MAX; SC(c0, q0) SC(c1, q1) SC(c2, q2) SC(c3, q3) }
  RESCAN();

  // per-wave top-10 (no barriers)
#pragma unroll
  for (int r = 0; r < KTOP; ++r) {
    float wv = bv; int wi = bi;
    wargmax(wv, wi);
    if (lane == 0) { wcv[wid * KTOP + r] = wv; wci[wid * KTOP + r] = wi; }
    if (bi == wi && wv > -INFINITY) {
      // invalidate my winning slot, recompute local argmax
#define INV(CQ, Q)                                                           \
      { _Pragma("unroll") for (int l = 0; l < 4; ++l) {                      \
          int ii = (((g_lo + (Q)) << 2) + l);                                \
          if ((Q) < ng && ii == wi) CQ[l] = -INFINITY; } }
      INV(c0, q0) INV(c1, q1) INV(c2, q2) INV(c3, q3)
#undef INV
      RESCAN();
    }
  }
#undef RESCAN
#undef SC

  float wmn = wredMin(lmin), wsm = wredSum(lsum);
  if (lane == 0) { rmn[wid] = wmn; rsm[wid] = wsm; }
  __syncthreads();

  // wave 0: merge 4 wave-top10s (40 entries) -> segment top-10; reduce stats
  if (wid == 0) {
    if (lane == 0) {
      smin[rs] = fminf(fminf(rmn[0], rmn[1]), fminf(rmn[2], rmn[3]));
      ssum[rs] = rsm[0] + rsm[1] + rsm[2] + rsm[3];
    }
    float mv = (lane < 4 * KTOP) ? wcv[lane] : -INFINITY;
    int   mi = (lane < 4 * KTOP) ? wci[lane] : INT_MAX;
#pragma unroll
    for (int r = 0; r < KTOP; ++r) {
      float wv = mv; int wi = mi;
      wargmax(wv, wi);
      if (lane == r) { cv[(size_t)rs * KTOP + r] = wv; ci[(size_t)rs * KTOP + r] = wi; }
      if (mi == wi) mv = -INFINITY;
    }
  }
}

// ---------------- K2: per-row merge + constants ----------------
__global__ __launch_bounds__(64) void k2_row(
    const float* __restrict__ zg, const int* __restrict__ yv,
    const float* __restrict__ smin, const float* __restrict__ ssum,
    const float* __restrict__ cv, const int* __restrict__ ci,
    float* __restrict__ rowc, int* __restrict__ rowi, int B, int C) {
  const int row  = blockIdx.x;
  const int lane = threadIdx.x;
  const int y    = yv[row];

  float mn = (lane < SEGS) ? smin[row * SEGS + lane] : INFINITY;
  float sm = (lane < SEGS) ? ssum[row * SEGS + lane] : 0.0f;
  mn = wredMin(mn);
  sm = wredSum(sm);

  const int NC = SEGS * KTOP;  // 80 candidates
  const float* cvr = cv + (size_t)row * NC;
  const int*   cir = ci + (size_t)row * NC;
  float v0 = (lane < NC) ? cvr[lane] : -INFINITY;
  int   i0 = (lane < NC) ? cir[lane] : INT_MAX;
  float v1 = (lane + 64 < NC) ? cvr[lane + 64] : -INFINITY;
  int   i1 = (lane + 64 < NC) ? cir[lane + 64] : INT_MAX;

  float myv = -INFINITY; int myi = INT_MAX;
  float Stop = 0.0f;
#pragma unroll
  for (int r = 0; r < KTOP; ++r) {
    float bv = v0; int bi = i0;
    if (v1 > bv || (v1 == bv && i1 < bi)) { bv = v1; bi = i1; }
    wargmax(bv, bi);
    Stop += __expf(bv);
    if (lane == r) { myv = bv; myi = bi; }
    if (i0 == bi) v0 = -INFINITY;
    if (i1 == bi) v1 = -INFINITY;
  }

  const float zy   = zg[(size_t)row * C + y];
  const float Sall = sm - __expf(zy);        // non-true sum (same math as R8, verified)
  const float ev   = __expf(mn);
  const float invZ = 1.0f / (Sall + ev);     // Z = S_nt + e^v exactly
  float Srest = Sall - Stop;
  if (Srest < 0.0f) Srest = 0.0f;
  float MR = (float)(C - 1 - KTOP);
  if (MR < 1.0f) MR = 1.0f;

  if (lane == 0) {
    rowc[row * 12 + 0] = (Srest / MR) * invZ;  // p_rest
    rowc[row * 12 + 1] = ev * invZ;            // p_true
  }
  if (lane < KTOP) {
    rowc[row * 12 + 2 + lane] = __expf(myv) * invZ;  // pk
    rowi[row * KTOP + lane]   = myi;                 // ki
  }
}

// ---------------- K3: pure fill of one segment ----------------
__global__ __launch_bounds__(TPB3) void k3_fill(
    const float* __restrict__ rowc, const int* __restrict__ rowi,
    const int* __restrict__ yv, float* __restrict__ out, int B, int C) {
  const int rs  = blockIdx.x;
  const int row = rs / SEGS, seg = rs - row * SEGS;
  const int C4  = C >> 2;
  const int L4  = (C4 + SEGS - 1) / SEGS;
  const int g_lo = seg * L4;
  const int g_hi = min(g_lo + L4, C4);
  const int tid = threadIdx.x;

  const float p_rest = rowc[row * 12 + 0];
  const float p_true = rowc[row * 12 + 1];
  float pk[KTOP]; int ki[KTOP]; int sv[KTOP];
#pragma unroll
  for (int k = 0; k < KTOP; ++k) {
    pk[k] = rowc[row * 12 + 2 + k];
    ki[k] = rowi[row * KTOP + k];
    sv[k] = ki[k] >> 2;
  }
  const int y = yv[row];
  const int svy = y >> 2;

  floatx4* out4 = (floatx4*)(out + (size_t)row * C);
  const floatx4 fillv = {p_rest, p_rest, p_rest, p_rest};
#pragma unroll
  for (int k4 = 0; k4 < 4; ++k4) {
    int g = g_lo + tid + k4 * TPB3;
    if (g < g_hi) {
      floatx4 o = fillv;
      bool sp = (g == svy);
#pragma unroll
      for (int k = 0; k < KTOP; ++k) sp |= (g == sv[k]);
      if (sp) {
        int j = g << 2;
#pragma unroll
        for (int l = 0; l < 4; ++l) {
          float p = p_rest;
#pragma unroll
          for (int k = 0; k < KTOP; ++k)
            if (j + l == ki[k]) p = pk[k];
          if (j + l == y) p = p_true;
          o[l] = p;
        }
      }
      __builtin_nontemporal_store(o, &out4[g]);
    }
  }
}

extern "C" void kernel_launch(void* const* d_in, const int* in_sizes, int n_in,
                              void* d_out, int out_size, void* d_ws, size_t ws_size,
                              hipStream_t stream) {
  const float* zg = (const float*)d_in[0];
  const int* y    = (const int*)d_in[1];
  float* out      = (float*)d_out;
  const int B = in_sizes[1];
  const int C = in_sizes[0] / B;
  const int RS = B * SEGS;

  // ws layout (floats/ints, 4B each):
  //   smin[RS] | ssum[RS] | cv[RS*KTOP] | ci[RS*KTOP] | rowc[B*12] | rowi[B*KTOP]
  // = RS*22 + B*22 words  ~= 3.2 MB for B=4096, SEGS=8
  float* smin = (float*)d_ws;
  float* ssum = smin + RS;
  float* cv   = ssum + RS;
  int*   ci   = (int*)(cv + (size_t)RS * KTOP);
  float* rowc = (float*)(ci + (size_t)RS * KTOP);
  int*   rowi = (int*)(rowc + (size_t)B * 12);

  k1_seg<<<RS, TPB1, 0, stream>>>(zg, y, smin, ssum, cv, ci, B, C);
  k2_row<<<B, 64, 0, stream>>>(zg, y, smin, ssum, cv, ci, rowc, rowi, B, C);
  k3_fill<<<RS, TPB3, 0, stream>>>(rowc, rowi, y, out, B, C);
}

// Round 10
// 341.040 us; speedup vs baseline: 2.8504x; 1.8516x over previous
//
#include <hip/hip_runtime.h>
#include <math.h>

#define SEGS 8
#define KTOP 10
#define TPB1 256
#define TPB3 256
#define CAP  160
#define TCAND 11.0f

typedef float floatx4 __attribute__((ext_vector_type(4)));
typedef unsigned long long u64;
typedef unsigned int u32;

__device__ inline float wredMin(float v) {
#pragma unroll
  for (int o = 32; o >= 1; o >>= 1) v = fminf(v, __shfl_xor(v, o));
  return v;
}
__device__ inline float wredSum(float v) {
#pragma unroll
  for (int o = 32; o >= 1; o >>= 1) v += __shfl_xor(v, o);
  return v;
}
__device__ inline int wredSumI(int v) {
#pragma unroll
  for (int o = 32; o >= 1; o >>= 1) v += __shfl_xor(v, o);
  return v;
}
__device__ inline u64 shfl_xor_u64(u64 k, int o) {
  int lo = __shfl_xor((int)(u32)k, o);
  int hi = __shfl_xor((int)(u32)(k >> 32), o);
  return ((u64)(u32)hi << 32) | (u32)lo;
}
__device__ inline u64 wredMaxU64(u64 k) {
#pragma unroll
  for (int o = 32; o >= 1; o >>= 1) {
    u64 ok = shfl_xor_u64(k, o);
    if (ok > k) k = ok;
  }
  return k;
}
// key order == (value desc, index asc): monotone float->u32 map in high word, ~idx low
__device__ inline u64 mkkey(float z, int idx) {
  u32 b = __float_as_uint(z);
  u32 u = (b & 0x80000000u) ? ~b : (b | 0x80000000u);
  return ((u64)u << 32) | (u32)~(u32)idx;
}
__device__ inline int keyidx(u64 k) { return (int)~(u32)k; }
__device__ inline float keyval(u64 k) {
  u32 u = (u32)(k >> 32);
  u32 b = (u & 0x80000000u) ? (u ^ 0x80000000u) : ~u;
  return __uint_as_float(b);
}

// ---- K1: pure stream. Per-segment min / sum-exp (incl. y); candidates > TCAND
// pushed to per-row global pool. NO selection logic in-pass.
__global__ __launch_bounds__(TPB1) void k1_stream(
    const float* __restrict__ zg,
    float* __restrict__ smin, float* __restrict__ ssum,
    int* __restrict__ cnt, u64* __restrict__ pool, int B, int C) {
  __shared__ float rmn[TPB1 / 64], rsm[TPB1 / 64];
  const int rs  = blockIdx.x;
  const int row = rs / SEGS, seg = rs - row * SEGS;
  const int C4  = C >> 2;
  const int L4  = (C4 + SEGS - 1) / SEGS;
  const int g_lo = seg * L4;
  const int g_hi = min(g_lo + L4, C4);
  const floatx4* zr4 = (const floatx4*)(zg + (size_t)row * C);
  const int tid = threadIdx.x, wid = tid >> 6, lane = tid & 63;

  int* crow = cnt + row;
  u64* prow = pool + (size_t)row * CAP;

  float lmin = INFINITY, lsum = 0.0f;

  for (int base = g_lo; base < g_hi; base += 4 * TPB1) {
    const int q0 = base + tid, q1 = q0 + TPB1, q2 = q1 + TPB1, q3 = q2 + TPB1;
    const bool h0 = q0 < g_hi, h1 = q1 < g_hi, h2 = q2 < g_hi, h3 = q3 < g_hi;
    floatx4 x0 = {0, 0, 0, 0}, x1 = {0, 0, 0, 0}, x2 = {0, 0, 0, 0}, x3 = {0, 0, 0, 0};
    if (h0) x0 = zr4[q0];
    if (h1) x1 = zr4[q1];
    if (h2) x2 = zr4[q2];
    if (h3) x3 = zr4[q3];
#define PROC(X, H, Q)                                                                              \
    if (H) {                                                                                       \
      lmin = fminf(lmin, fminf(fminf(X.x, X.y), fminf(X.z, X.w)));                                 \
      lsum += __expf(X.x) + __expf(X.y) + __expf(X.z) + __expf(X.w);                               \
      if (fmaxf(fmaxf(X.x, X.y), fmaxf(X.z, X.w)) > TCAND) {                                       \
        int j = (Q) << 2;                                                                          \
        if (X.x > TCAND) { int p = atomicAdd(crow, 1); if (p < CAP) prow[p] = mkkey(X.x, j); }     \
        if (X.y > TCAND) { int p = atomicAdd(crow, 1); if (p < CAP) prow[p] = mkkey(X.y, j + 1); } \
        if (X.z > TCAND) { int p = atomicAdd(crow, 1); if (p < CAP) prow[p] = mkkey(X.z, j + 2); } \
        if (X.w > TCAND) { int p = atomicAdd(crow, 1); if (p < CAP) prow[p] = mkkey(X.w, j + 3); } \
      }                                                                                            \
    }
    PROC(x0, h0, q0) PROC(x1, h1, q1) PROC(x2, h2, q2) PROC(x3, h3, q3)
#undef PROC
  }
  if (seg == SEGS - 1) {  // scalar tail (C % 4 != 0 only)
    const float* zr = zg + (size_t)row * C;
    for (int j = (C4 << 2) + tid; j < C; j += TPB1) {
      float z = zr[j];
      lmin = fminf(lmin, z);
      lsum += __expf(z);
      if (z > TCAND) { int p = atomicAdd(crow, 1); if (p < CAP) prow[p] = mkkey(z, j); }
    }
  }

  lmin = wredMin(lmin);
  lsum = wredSum(lsum);
  if (lane == 0) { rmn[wid] = lmin; rsm[wid] = lsum; }
  __syncthreads();
  if (tid == 0) {
    float mn = INFINITY, sm = 0.0f;
#pragma unroll
    for (int w = 0; w < TPB1 / 64; ++w) { mn = fminf(mn, rmn[w]); sm += rsm[w]; }
    smin[rs] = mn;
    ssum[rs] = sm;
  }
}

// ---- K2: per-row (1 wave). Merge stats; top-10 from pool (y-excluded) via
// prev-bounded u64 wave-max; full-row fallback if pool invalid; constants.
__global__ __launch_bounds__(64) void k2_row(
    const float* __restrict__ zg, const int* __restrict__ yv,
    const float* __restrict__ smin, const float* __restrict__ ssum,
    const int* __restrict__ cnt, const u64* __restrict__ pool,
    float* __restrict__ rowc, int* __restrict__ rowi, int B, int C) {
  const int row = blockIdx.x, lane = threadIdx.x;
  const int y = yv[row];
  const int Keff = KTOP < (C - 1) ? KTOP : (C - 1);

  float mn = (lane < SEGS) ? smin[row * SEGS + lane] : INFINITY;
  float sm = (lane < SEGS) ? ssum[row * SEGS + lane] : 0.0f;
  mn = wredMin(mn);
  sm = wredSum(sm);

  const int craw = cnt[row];
  u64 s0 = 0, s1 = 0, s2 = 0;
  bool ok = (craw <= CAP);
  if (ok) {
    const u64* pr = pool + (size_t)row * CAP;
    int nvl = 0;
    if (lane < craw)       { u64 k = pr[lane];       if (keyidx(k) != y) { s0 = k; ++nvl; } }
    if (lane + 64 < craw)  { u64 k = pr[lane + 64];  if (keyidx(k) != y) { s1 = k; ++nvl; } }
    if (lane + 128 < craw) { u64 k = pr[lane + 128]; if (keyidx(k) != y) { s2 = k; ++nvl; } }
    ok = (wredSumI(nvl) >= Keff);
  }
  const float* zr = zg + (size_t)row * C;

  u64 sel[KTOP];
  u64 prev = ~0ull;
#pragma unroll
  for (int r = 0; r < KTOP; ++r) {
    u64 loc = 0;
    if (r < Keff) {
      if (ok) {
        if (s0 < prev && s0 > loc) loc = s0;
        if (s1 < prev && s1 > loc) loc = s1;
        if (s2 < prev && s2 > loc) loc = s2;
      } else {
        for (int j = lane; j < C; j += 64) {
          if (j == y) continue;
          u64 k = mkkey(zr[j], j);
          if (k < prev && k > loc) loc = k;
        }
      }
    }
    u64 best = wredMaxU64(loc);
    sel[r] = best;
    prev = best;
  }

  float Stop = 0.0f;
#pragma unroll
  for (int r = 0; r < KTOP; ++r)
    if (r < Keff && sel[r] != 0) Stop += __expf(keyval(sel[r]));

  const float zy   = zr[y];
  const float Sall = sm - __expf(zy);       // non-true sum-exp
  const float ev   = __expf(mn);
  const float invZ = 1.0f / (Sall + ev);    // Z = S_nt + e^v exactly
  float Srest = Sall - Stop;
  if (Srest < 0.0f) Srest = 0.0f;
  float MR = (float)(C - 1 - Keff);
  if (MR < 1.0f) MR = 1.0f;

  if (lane == 0) {
    rowc[row * 12 + 0] = (Srest / MR) * invZ;   // p_rest
    rowc[row * 12 + 1] = ev * invZ;             // p_true
#pragma unroll
    for (int r = 0; r < KTOP; ++r) {
      bool have = (r < Keff) && (sel[r] != 0);
      rowc[row * 12 + 2 + r] = have ? __expf(keyval(sel[r])) * invZ : 0.0f;
      rowi[row * KTOP + r]   = have ? keyidx(sel[r]) : -1;
    }
  }
}

// ---- K3: pure fill of one segment from 22 row constants ----
__global__ __launch_bounds__(TPB3) void k3_fill(
    const float* __restrict__ rowc, const int* __restrict__ rowi,
    const int* __restrict__ yv, float* __restrict__ out, int B, int C) {
  const int rs  = blockIdx.x;
  const int row = rs / SEGS, seg = rs - row * SEGS;
  const int C4  = C >> 2;
  const int L4  = (C4 + SEGS - 1) / SEGS;
  const int g_lo = seg * L4;
  const int g_hi = min(g_lo + L4, C4);
  const int tid = threadIdx.x;

  const float p_rest = rowc[row * 12 + 0];
  const float p_true = rowc[row * 12 + 1];
  float pk[KTOP]; int ki[KTOP]; int sv[KTOP];
#pragma unroll
  for (int k = 0; k < KTOP; ++k) {
    pk[k] = rowc[row * 12 + 2 + k];
    ki[k] = rowi[row * KTOP + k];
    sv[k] = ki[k] >> 2;            // -1 for absent -> never matches
  }
  const int y = yv[row];
  const int svy = y >> 2;

  float* orow = out + (size_t)row * C;
  floatx4* out4 = (floatx4*)orow;
  const floatx4 fillv = {p_rest, p_rest, p_rest, p_rest};
  for (int g = g_lo + tid; g < g_hi; g += TPB3) {
    floatx4 o = fillv;
    bool sp = (g == svy);
#pragma unroll
    for (int k = 0; k < KTOP; ++k) sp |= (g == sv[k]);
    if (sp) {
      int j = g << 2;
#pragma unroll
      for (int l = 0; l < 4; ++l) {
        float p = p_rest;
#pragma unroll
        for (int k = 0; k < KTOP; ++k)
          if (j + l == ki[k]) p = pk[k];
        if (j + l == y) p = p_true;
        o[l] = p;
      }
    }
    __builtin_nontemporal_store(o, &out4[g]);
  }
  if (seg == SEGS - 1) {  // scalar tail
    for (int j = (C4 << 2) + tid; j < C; j += TPB3) {
      float p = p_rest;
#pragma unroll
      for (int k = 0; k < KTOP; ++k)
        if (j == ki[k]) p = pk[k];
      if (j == y) p = p_true;
      __builtin_nontemporal_store(p, &orow[j]);
    }
  }
}

extern "C" void kernel_launch(void* const* d_in, const int* in_sizes, int n_in,
                              void* d_out, int out_size, void* d_ws, size_t ws_size,
                              hipStream_t stream) {
  const float* zg = (const float*)d_in[0];
  const int* y    = (const int*)d_in[1];
  float* out      = (float*)d_out;
  const int B = in_sizes[1];
  const int C = in_sizes[0] / B;
  const int RS = B * SEGS;

  // ws layout: cnt[B] | smin[RS] | ssum[RS] | rowc[B*12] | rowi[B*KTOP] | pool[B*CAP] (u64, 8B-aligned)
  char* base  = (char*)d_ws;
  int*   cnt  = (int*)base;
  float* smin = (float*)(cnt + B);
  float* ssum = smin + RS;
  float* rowc = ssum + RS;
  int*   rowi = (int*)(rowc + (size_t)B * 12);
  size_t used = (size_t)B * 4 + (size_t)RS * 8 + (size_t)B * 48 + (size_t)B * KTOP * 4;
  used = (used + 7) & ~(size_t)7;
  u64* pool = (u64*)(base + used);

  hipMemsetAsync(cnt, 0, (size_t)B * sizeof(int), stream);
  k1_stream<<<RS, TPB1, 0, stream>>>(zg, smin, ssum, cnt, pool, B, C);
  k2_row<<<B, 64, 0, stream>>>(zg, y, smin, ssum, cnt, pool, rowc, rowi, B, C);
  k3_fill<<<RS, TPB3, 0, stream>>>(rowc, rowi, y, out, B, C);
}

// Round 11
// 201.733 us; speedup vs baseline: 4.8187x; 1.6905x over previous
//
#include <hip/hip_runtime.h>
#include <math.h>

#define TPB 256
#define NW (TPB / 64)
#define CAP 256
#define KTOP 10
#define TCAND 11.0f

typedef float floatx4 __attribute__((ext_vector_type(4)));
typedef unsigned long long u64;
typedef unsigned int u32;

__device__ inline float wredMin(float v) {
#pragma unroll
  for (int o = 32; o >= 1; o >>= 1) v = fminf(v, __shfl_xor(v, o));
  return v;
}
__device__ inline float wredSum(float v) {
#pragma unroll
  for (int o = 32; o >= 1; o >>= 1) v += __shfl_xor(v, o);
  return v;
}
__device__ inline u64 shfl_xor_u64(u64 k, int o) {
  int lo = __shfl_xor((int)(u32)k, o);
  int hi = __shfl_xor((int)(u32)(k >> 32), o);
  return ((u64)(u32)hi << 32) | (u32)lo;
}
__device__ inline u64 wredMaxU64(u64 k) {
#pragma unroll
  for (int o = 32; o >= 1; o >>= 1) {
    u64 ok = shfl_xor_u64(k, o);
    if (ok > k) k = ok;
  }
  return k;
}
// key order == (value desc, index asc): monotone float->u32 in high word, ~idx low.
// 0 is a safe "absent" sentinel (no positive logit maps to 0).
__device__ inline u64 mkkey(float z, int idx) {
  u32 b = __float_as_uint(z);
  u32 u = (b & 0x80000000u) ? ~b : (b | 0x80000000u);
  return ((u64)u << 32) | (u32)~(u32)idx;
}
__device__ inline int keyidx(u64 k) { return (int)~(u32)k; }
__device__ inline float keyval(u64 k) {
  u32 u = (u32)(k >> 32);
  u32 b = (u & 0x80000000u) ? (u ^ 0x80000000u) : ~u;
  return __uint_as_float(b);
}

struct SM {
  u64 pool[CAP];
  u64 warr[NW];          // block u64-max staging (fallback)
  u64 selArr[KTOP];      // fallback-selected keys
  float rmn[NW], rsm[NW];
  int cnt;
  float c_prest, c_ptrue;
  float pk[KTOP];
  int ki[KTOP];
};

__global__ __launch_bounds__(TPB) void fused(
    const float* __restrict__ zg, const int* __restrict__ yv,
    float* __restrict__ out, int B, int C) {
  __shared__ SM S;

  const int tid = threadIdx.x, wid = tid >> 6, lane = tid & 63;
  const int row = blockIdx.x;
  const float* zr = zg + (size_t)row * C;
  const floatx4* zr4 = (const floatx4*)zr;
  const int C4 = C >> 2;
  const int y = yv[row];
  const int Keff = KTOP < (C - 1) ? KTOP : (C - 1);

  float zy0 = 0.0f;
  if (tid == 0) { S.cnt = 0; zy0 = zr[y]; }
  __syncthreads();

  // ---- Phase 1: single streamed read. min(all), sum exp(all); candidates
  // > TCAND (y excluded) -> LDS pool as u64 keys. No re-reads, no retries.
  float lmin = INFINITY, lsum = 0.0f;
  for (int base = 0; base < C4; base += 4 * TPB) {
    const int q0 = base + tid, q1 = q0 + TPB, q2 = q1 + TPB, q3 = q2 + TPB;
    const bool h0 = q0 < C4, h1 = q1 < C4, h2 = q2 < C4, h3 = q3 < C4;
    floatx4 x0 = {0, 0, 0, 0}, x1 = {0, 0, 0, 0}, x2 = {0, 0, 0, 0}, x3 = {0, 0, 0, 0};
    if (h0) x0 = __builtin_nontemporal_load(zr4 + q0);
    if (h1) x1 = __builtin_nontemporal_load(zr4 + q1);
    if (h2) x2 = __builtin_nontemporal_load(zr4 + q2);
    if (h3) x3 = __builtin_nontemporal_load(zr4 + q3);
#define PROC(X, H, Q)                                                                        \
    if (H) {                                                                                 \
      lmin = fminf(lmin, fminf(fminf(X.x, X.y), fminf(X.z, X.w)));                           \
      lsum += __expf(X.x) + __expf(X.y) + __expf(X.z) + __expf(X.w);                         \
      if (fmaxf(fmaxf(X.x, X.y), fmaxf(X.z, X.w)) > TCAND) {                                 \
        int j = (Q) << 2;                                                                    \
        if (X.x > TCAND && j + 0 != y) { int p = atomicAdd(&S.cnt, 1); if (p < CAP) S.pool[p] = mkkey(X.x, j); }     \
        if (X.y > TCAND && j + 1 != y) { int p = atomicAdd(&S.cnt, 1); if (p < CAP) S.pool[p] = mkkey(X.y, j + 1); } \
        if (X.z > TCAND && j + 2 != y) { int p = atomicAdd(&S.cnt, 1); if (p < CAP) S.pool[p] = mkkey(X.z, j + 2); } \
        if (X.w > TCAND && j + 3 != y) { int p = atomicAdd(&S.cnt, 1); if (p < CAP) S.pool[p] = mkkey(X.w, j + 3); } \
      }                                                                                      \
    }
    PROC(x0, h0, q0) PROC(x1, h1, q1) PROC(x2, h2, q2) PROC(x3, h3, q3)
#undef PROC
  }
  for (int j = (C4 << 2) + tid; j < C; j += TPB) {  // scalar tail (C%4!=0 only)
    float z = zr[j];
    lmin = fminf(lmin, z);
    lsum += __expf(z);
    if (z > TCAND && j != y) { int p = atomicAdd(&S.cnt, 1); if (p < CAP) S.pool[p] = mkkey(z, j); }
  }

  lmin = wredMin(lmin);
  lsum = wredSum(lsum);
  if (lane == 0) { S.rmn[wid] = lmin; S.rsm[wid] = lsum; }
  __syncthreads();

  const int pc = S.cnt;                       // block-uniform
  float vmin = INFINITY, total = 0.0f;
#pragma unroll
  for (int w = 0; w < NW; ++w) { vmin = fminf(vmin, S.rmn[w]); total += S.rsm[w]; }
  const bool ok = (pc >= Keff && pc <= CAP);  // block-uniform

  // ---- Phase 2: top-Keff selection (value desc, index asc == jax stable) ----
  if (ok) {
    if (wid == 0) {  // barrier-free: wave 0, pool in registers, prev-bounded max
      u64 s0 = (lane < pc)       ? S.pool[lane]       : 0;
      u64 s1 = (lane + 64 < pc)  ? S.pool[lane + 64]  : 0;
      u64 s2 = (lane + 128 < pc) ? S.pool[lane + 128] : 0;
      u64 s3 = (lane + 192 < pc) ? S.pool[lane + 192] : 0;
      u64 sel[KTOP];
      u64 prev = ~0ull;
#pragma unroll
      for (int r = 0; r < KTOP; ++r) {
        u64 loc = 0;
        if (r < Keff) {
          if (s0 < prev && s0 > loc) loc = s0;
          if (s1 < prev && s1 > loc) loc = s1;
          if (s2 < prev && s2 > loc) loc = s2;
          if (s3 < prev && s3 > loc) loc = s3;
        }
        u64 best = wredMaxU64(loc);
        sel[r] = best;
        prev = best;
      }
      if (lane == 0) {
        float Stop = 0.0f;
#pragma unroll
        for (int r = 0; r < KTOP; ++r)
          if (sel[r] != 0) Stop += __expf(keyval(sel[r]));
        const float Sall = total - __expf(zy0);
        const float ev   = __expf(vmin);
        const float invZ = 1.0f / (Sall + ev);
        float Srest = Sall - Stop;
        if (Srest < 0.0f) Srest = 0.0f;
        float MR = (float)(C - 1 - Keff);
        if (MR < 1.0f) MR = 1.0f;
        S.c_prest = (Srest / MR) * invZ;
        S.c_ptrue = ev * invZ;
#pragma unroll
        for (int r = 0; r < KTOP; ++r) {
          bool have = (sel[r] != 0);
          S.pk[r] = have ? __expf(keyval(sel[r])) * invZ : 0.0f;
          S.ki[r] = have ? keyidx(sel[r]) : -1;
        }
      }
    }
  } else {
    // Guaranteed-exact fallback (pathological; ~never taken): block-wide
    // prev-bounded u64 max over the full row, Keff rounds.
    u64 prev = ~0ull;
    for (int r = 0; r < KTOP; ++r) {
      u64 loc = 0;
      if (r < Keff) {
        for (int j = tid; j < C; j += TPB) {
          if (j == y) continue;
          u64 k = mkkey(zr[j], j);
          if (k < prev && k > loc) loc = k;
        }
      }
      u64 best = wredMaxU64(loc);
      if (lane == 0) S.warr[wid] = best;
      __syncthreads();
      if (tid == 0) {
        u64 b = 0;
#pragma unroll
        for (int w = 0; w < NW; ++w) b = (S.warr[w] > b) ? S.warr[w] : b;
        S.selArr[r] = b;
      }
      __syncthreads();
      prev = S.selArr[r];
    }
    if (tid == 0) {
      float Stop = 0.0f;
#pragma unroll
      for (int r = 0; r < KTOP; ++r)
        if (S.selArr[r] != 0) Stop += __expf(keyval(S.selArr[r]));
      const float Sall = total - __expf(zy0);
      const float ev   = __expf(vmin);
      const float invZ = 1.0f / (Sall + ev);
      float Srest = Sall - Stop;
      if (Srest < 0.0f) Srest = 0.0f;
      float MR = (float)(C - 1 - Keff);
      if (MR < 1.0f) MR = 1.0f;
      S.c_prest = (Srest / MR) * invZ;
      S.c_ptrue = ev * invZ;
#pragma unroll
      for (int r = 0; r < KTOP; ++r) {
        bool have = (S.selArr[r] != 0);
        S.pk[r] = have ? __expf(keyval(S.selArr[r])) * invZ : 0.0f;
        S.ki[r] = have ? keyidx(S.selArr[r]) : -1;
      }
    }
  }
  __syncthreads();

  // ---- Phase 3: pure fill write. No input reads. ----
  const float p_rest = S.c_prest;
  const float p_true = S.c_ptrue;
  float pk[KTOP]; int ki[KTOP]; int sv[KTOP];
#pragma unroll
  for (int k = 0; k < KTOP; ++k) {
    pk[k] = S.pk[k];
    ki[k] = S.ki[k];
    sv[k] = ki[k] >> 2;    // -1 for absent -> group -1, never matches
  }
  const int svy = y >> 2;

  float* orow = out + (size_t)row * C;
  floatx4* out4 = (floatx4*)orow;
  const floatx4 fillv = {p_rest, p_rest, p_rest, p_rest};
  for (int base = 0; base < C4; base += 4 * TPB) {
#pragma unroll
    for (int u = 0; u < 4; ++u) {
      int g = base + tid + u * TPB;
      if (g < C4) {
        floatx4 o = fillv;
        bool sp = (g == svy);
#pragma unroll
        for (int k = 0; k < KTOP; ++k) sp |= (g == sv[k]);
        if (sp) {
          int j = g << 2;
#pragma unroll
          for (int l = 0; l < 4; ++l) {
            float p = p_rest;
#pragma unroll
            for (int k = 0; k < KTOP; ++k)
              if (j + l == ki[k]) p = pk[k];
            if (j + l == y) p = p_true;
            o[l] = p;
          }
        }
        __builtin_nontemporal_store(o, &out4[g]);
      }
    }
  }
  for (int j = (C4 << 2) + tid; j < C; j += TPB) {  // scalar tail
    float p = p_rest;
#pragma unroll
    for (int k = 0; k < KTOP; ++k)
      if (j == ki[k]) p = pk[k];
    if (j == y) p = p_true;
    __builtin_nontemporal_store(p, &orow[j]);
  }
}

extern "C" void kernel_launch(void* const* d_in, const int* in_sizes, int n_in,
                              void* d_out, int out_size, void* d_ws, size_t ws_size,
                              hipStream_t stream) {
  const float* zg = (const float*)d_in[0];
  const int* y    = (const int*)d_in[1];
  float* out      = (float*)d_out;
  const int B = in_sizes[1];
  const int C = in_sizes[0] / B;

  fused<<<B, TPB, 0, stream>>>(zg, y, out, B, C);
}